// Round 7
// baseline (815.664 us; speedup 1.0000x reference)
//
#include <hip/hip_runtime.h>
#include <hip/hip_bf16.h>

typedef __attribute__((ext_vector_type(8))) short bf16x8;
typedef __attribute__((ext_vector_type(4))) float f32x4;

#define NPB 512      // nodes per dst-bucket (9 bits)
#define EPB 8192     // edges per partition/hist block

static __device__ __forceinline__ short f2bf(float v) {
  __hip_bfloat16 b = __float2bfloat16(v);   // RNE
  return __builtin_bit_cast(short, b);
}
static __device__ __forceinline__ float bf2f(unsigned short u) {
  union { unsigned u; float f; } c; c.u = (unsigned)u << 16; return c.f;
}

// ---------------- generic ----------------
__global__ void zero_int(int* p, int n) {
  int i = blockIdx.x * blockDim.x + threadIdx.x;
  if (i < n) p[i] = 0;
}
__global__ void make_dinv2(const int* __restrict__ cnt, float* __restrict__ dinv, int n) {
  int i = blockIdx.x * blockDim.x + threadIdx.x;
  if (i < n) dinv[i] = rsqrtf(1.0f + (float)cnt[i]);   // +1 self loop
}

// ---------------- bucketed CSR build ----------------
__global__ __launch_bounds__(256) void bucket_hist(const int* __restrict__ dst,
                                                   int* __restrict__ bucket_cnt, int e, int nb) {
  __shared__ int lh[256];
  int t = threadIdx.x;
  lh[t] = 0;
  __syncthreads();
  int c0 = blockIdx.x * EPB, c1 = min(c0 + EPB, e);
  for (int i = c0 + t; i < c1; i += 256) atomicAdd(&lh[dst[i] >> 9], 1);
  __syncthreads();
  if (t < nb && lh[t] > 0) atomicAdd(&bucket_cnt[t], lh[t]);
}
__global__ void bucket_scan(const int* __restrict__ bucket_cnt, int* __restrict__ base,
                            int* __restrict__ gcursor, int nb, int e) {
  __shared__ int s[256];
  int t = threadIdx.x;
  int v = (t < nb) ? bucket_cnt[t] : 0;
  s[t] = v;
  __syncthreads();
  for (int off = 1; off < 256; off <<= 1) {
    int val = (t >= off) ? s[t - off] : 0;
    __syncthreads();
    s[t] += val;
    __syncthreads();
  }
  if (t < nb) { int b = s[t] - v; base[t] = b; gcursor[t] = b; }
  if (t == 0) base[nb] = e;
}
// packed entry: (local_dst[9b] << 17) | src[17b]   (requires n <= 131072)
__global__ __launch_bounds__(256) void bucket_partition(const int* __restrict__ src,
    const int* __restrict__ dst, int* __restrict__ gcursor, int* __restrict__ ebuf,
    int e, int nb) {
  __shared__ int lh[256];
  __shared__ int lbase[256];
  int t = threadIdx.x;
  lh[t] = 0;
  __syncthreads();
  int c0 = blockIdx.x * EPB, c1 = min(c0 + EPB, e);
  for (int i = c0 + t; i < c1; i += 256) atomicAdd(&lh[dst[i] >> 9], 1);
  __syncthreads();
  if (t < nb && lh[t] > 0) lbase[t] = atomicAdd(&gcursor[t], lh[t]);
  lh[t] = 0;           // becomes per-bucket rank cursor
  __syncthreads();
  for (int i = c0 + t; i < c1; i += 256) {
    int d = dst[i], b = d >> 9;
    int r = atomicAdd(&lh[b], 1);
    ebuf[lbase[b] + r] = ((d & (NPB - 1)) << 17) | src[i];
  }
}
__global__ __launch_bounds__(256) void node_count(const int* __restrict__ ebuf,
    const int* __restrict__ base, int* __restrict__ cnt, float* __restrict__ dinv, int n) {
  __shared__ int lc[NPB];
  int b = blockIdx.x;
  for (int i = threadIdx.x; i < NPB; i += 256) lc[i] = 0;
  __syncthreads();
  int b0 = base[b], b1 = base[b + 1];
  for (int i = b0 + threadIdx.x; i < b1; i += 256) atomicAdd(&lc[ebuf[i] >> 17], 1);
  __syncthreads();
  int g0 = b * NPB;
  for (int i = threadIdx.x; i < NPB; i += 256)
    if (g0 + i < n) {
      int c = lc[i];
      cnt[g0 + i] = c;
      dinv[g0 + i] = rsqrtf(1.0f + (float)c);
    }
}
// exclusive scan over n node counts -> rowptr[n+1]
__global__ __launch_bounds__(256) void scan1(const int* __restrict__ cnt, int* __restrict__ excl,
                                             int* __restrict__ blksum, int n) {
  __shared__ int tsum[256];
  int t = threadIdx.x;
  int idx = blockIdx.x * 1024 + t * 4;
  int4 v = {0, 0, 0, 0};
  if (idx + 3 < n) v = *(const int4*)(cnt + idx);
  else {
    if (idx < n) v.x = cnt[idx];
    if (idx + 1 < n) v.y = cnt[idx + 1];
    if (idx + 2 < n) v.z = cnt[idx + 2];
    if (idx + 3 < n) v.w = cnt[idx + 3];
  }
  int s = v.x + v.y + v.z + v.w;
  tsum[t] = s;
  __syncthreads();
  for (int off = 1; off < 256; off <<= 1) {
    int val = (t >= off) ? tsum[t - off] : 0;
    __syncthreads();
    tsum[t] += val;
    __syncthreads();
  }
  int e0 = tsum[t] - s;
  if (idx < n) excl[idx] = e0;
  if (idx + 1 < n) excl[idx + 1] = e0 + v.x;
  if (idx + 2 < n) excl[idx + 2] = e0 + v.x + v.y;
  if (idx + 3 < n) excl[idx + 3] = e0 + v.x + v.y + v.z;
  if (t == 255) blksum[blockIdx.x] = tsum[255];
}
__global__ void scan2(const int* __restrict__ blksum, int* __restrict__ blkoff, int nb) {
  __shared__ int s[256];
  int t = threadIdx.x;
  int v0 = (t < nb) ? blksum[t] : 0;
  s[t] = v0;
  __syncthreads();
  for (int off = 1; off < 256; off <<= 1) {
    int val = (t >= off) ? s[t - off] : 0;
    __syncthreads();
    s[t] += val;
    __syncthreads();
  }
  if (t < nb) blkoff[t] = s[t] - v0;
}
__global__ void scan3(int* __restrict__ rowptr, const int* __restrict__ blkoff, int n, int e) {
  int i = blockIdx.x * blockDim.x + threadIdx.x;
  if (i < n) rowptr[i] += blkoff[i >> 10];
  if (i == 0) rowptr[n] = e;
}
__global__ __launch_bounds__(256) void bucket_scatter(const int* __restrict__ ebuf,
    const int* __restrict__ base, const int* __restrict__ rowptr,
    int* __restrict__ ssrc, int n) {
  __shared__ int lcur[NPB];
  int b = blockIdx.x;
  int g0 = b * NPB;
  for (int i = threadIdx.x; i < NPB; i += 256)
    lcur[i] = (g0 + i < n) ? rowptr[g0 + i] : 0;
  __syncthreads();
  int b0 = base[b], b1 = base[b + 1];
  for (int i = b0 + threadIdx.x; i < b1; i += 256) {
    int p = ebuf[i];
    int pos = atomicAdd(&lcur[p >> 17], 1);
    ssrc[pos] = p & 0x1FFFF;
  }
}

// ---------------- GEMM0: [n,512] x [512,32], bf16 MFMA, bf16 out scaled by dinv ----------------
__global__ __launch_bounds__(256) void gemm0_mfma(
    const float* __restrict__ x, const float* __restrict__ W,
    const float* __restrict__ dinv, unsigned short* __restrict__ hb, int n) {
  __shared__ bf16x8 wp[2048];               // [ct(2)][ks(16)][lane(64)], 32KB
  int tid = threadIdx.x;
  for (int s = tid; s < 2048; s += 256) {
    int ct = s >> 10, rem = s & 1023, ks = rem >> 6, lane = rem & 63;
    int r = lane & 15, half = lane >> 4;
    int k0 = ks * 32 + half * 8;
    bf16x8 tmp;
#pragma unroll
    for (int j = 0; j < 8; ++j)
      tmp[j] = f2bf(W[(k0 + j) * 32 + ct * 16 + r]);
    wp[s] = tmp;
  }
  __syncthreads();
  int wave = tid >> 6, lane = tid & 63;
  int rowbase = blockIdx.x * 64 + wave * 16;
  int r = lane & 15, half = lane >> 4;
  int arow = rowbase + r; if (arow > n - 1) arow = n - 1;
  const float* xr = x + (size_t)arow * 512 + half * 8;
  f32x4 acc0 = {0.f, 0.f, 0.f, 0.f}, acc1 = {0.f, 0.f, 0.f, 0.f};
#pragma unroll
  for (int ks = 0; ks < 16; ++ks) {
    f32x4 a0 = *(const f32x4*)(xr + ks * 32);
    f32x4 a1 = *(const f32x4*)(xr + ks * 32 + 4);
    bf16x8 af;
    af[0] = f2bf(a0[0]); af[1] = f2bf(a0[1]); af[2] = f2bf(a0[2]); af[3] = f2bf(a0[3]);
    af[4] = f2bf(a1[0]); af[5] = f2bf(a1[1]); af[6] = f2bf(a1[2]); af[7] = f2bf(a1[3]);
    acc0 = __builtin_amdgcn_mfma_f32_16x16x32_bf16(af, wp[ks * 64 + lane], acc0, 0, 0, 0);
    acc1 = __builtin_amdgcn_mfma_f32_16x16x32_bf16(af, wp[1024 + ks * 64 + lane], acc1, 0, 0, 0);
  }
#pragma unroll
  for (int rg = 0; rg < 4; ++rg) {
    int row = rowbase + half * 4 + rg;      // C/D: col=lane&15, row=(lane>>4)*4+reg
    if (row < n) {
      float dv = dinv[row];
      hb[(size_t)row * 32 + r]      = (unsigned short)f2bf(acc0[rg] * dv);
      hb[(size_t)row * 32 + 16 + r] = (unsigned short)f2bf(acc1[rg] * dv);
    }
  }
}

// ---------------- gather aggregation, MLP-maximized ----------------
// out[d] = bias + dinv[d] * ( hb[d] + sum_{s in row d} hb[s] );  hb pre-scaled by dinv[src]
__global__ __launch_bounds__(256) void agg_gather32(
    const unsigned short* __restrict__ hb, const float* __restrict__ dinv,
    const float* __restrict__ bias, const int* __restrict__ rowptr,
    const int* __restrict__ ssrc, float* __restrict__ out, int n) {
  int wid = (int)((blockIdx.x * 256u + threadIdx.x) >> 6);
  int lane = threadIdx.x & 63;
  if (wid >= n) return;
  int f = lane & 31, half = lane >> 5;
  int r0 = rowptr[wid], r1 = rowptr[wid + 1];
  float acc = 0.f;
  for (int base = r0; base < r1; base += 64) {
    int cnt = min(64, r1 - base);
    int idx = ssrc[base + min(lane, cnt - 1)];   // coalesced preload of up to 64 indices
    // half h processes k = h, h+2, ... ; 8 independent gathers per unrolled body
    for (int g = 0; g < cnt; g += 16) {
#pragma unroll
      for (int u = 0; u < 8; ++u) {
        int k = g + half + 2 * u;
        int kc = min(k, cnt - 1);
        int s = __shfl(idx, kc, 64);
        float v = bf2f(hb[(size_t)s * 32 + f]);
        acc += (k < cnt) ? v : 0.f;
      }
    }
  }
  acc += __shfl_down(acc, 32, 64);
  if (lane < 32) {
    float self = bf2f(hb[(size_t)wid * 32 + f]);
    out[(size_t)wid * 32 + f] = bias[f] + dinv[wid] * (self + acc);
  }
}
__global__ __launch_bounds__(256) void agg_gather40(
    const unsigned short* __restrict__ hb, const float* __restrict__ dinv,
    const float* __restrict__ bias, const int* __restrict__ rowptr,
    const int* __restrict__ ssrc, float* __restrict__ out, int n) {
  int wid = (int)((blockIdx.x * 256u + threadIdx.x) >> 6);
  int lane = threadIdx.x & 63;
  if (wid >= n) return;
  int r0 = rowptr[wid], r1 = rowptr[wid + 1];
  float acc = 0.f;
  for (int base = r0; base < r1; base += 64) {
    int cnt = min(64, r1 - base);
    int idx = ssrc[base + min(lane, cnt - 1)];
    for (int g = 0; g < cnt; g += 8) {
#pragma unroll
      for (int u = 0; u < 8; ++u) {
        int k = g + u;
        int kc = min(k, cnt - 1);
        int s = __shfl(idx, kc, 64);
        float v = (lane < 40) ? bf2f(hb[(size_t)s * 40 + lane]) : 0.f;
        acc += (k < cnt) ? v : 0.f;
      }
    }
  }
  if (lane < 40) {
    float self = bf2f(hb[(size_t)wid * 40 + lane]);
    out[(size_t)wid * 40 + lane] = bias[lane] + dinv[wid] * (self + acc);
  }
}

// ---------------- fallback atomic path (bf16 hb) ----------------
__global__ void count_dst(const int* __restrict__ dst, int* __restrict__ cnt, int e) {
  int i = blockIdx.x * blockDim.x + threadIdx.x;
  if (i < e) atomicAdd(&cnt[dst[i]], 1);
}
template <int F>
__global__ void agg_init(const unsigned short* __restrict__ hb, const float* __restrict__ dinv,
                         const float* __restrict__ bias, float* __restrict__ out, int n) {
  int idx = blockIdx.x * blockDim.x + threadIdx.x;
  if (idx >= n * F) return;
  int i = idx / F, f = idx - i * F;
  out[idx] = bias[f] + bf2f(hb[idx]) * dinv[i];
}
template <int F>
__global__ void agg_edges(const unsigned short* __restrict__ hb, const float* __restrict__ dinv,
                          const int* __restrict__ src, const int* __restrict__ dst,
                          float* __restrict__ out, int e) {
  int t = blockIdx.x * blockDim.x + threadIdx.x;
  int edge = t / F, f = t - edge * F;
  if (edge >= e) return;
  int s = src[edge], d = dst[edge];
  atomicAdd(&out[d * F + f], bf2f(hb[s * F + f]) * dinv[d]);
}

// ---------------- pairnorm stats ----------------
__global__ void zero_stats(float* stats) {
  if (threadIdx.x < 128) stats[threadIdx.x] = 0.f;   // both layers' slots
}
__global__ void pn_stats(const float* __restrict__ x, float* __restrict__ stats, int n) {
  int tid = threadIdx.x;
  int gsize = gridDim.x * blockDim.x;
  float csum = 0.f, ssq = 0.f;
  for (int idx = blockIdx.x * blockDim.x + tid; idx < n * 32; idx += gsize) {
    float v = x[idx];
    csum += v; ssq += v * v;
  }
#pragma unroll
  for (int off = 32; off >= 1; off >>= 1) ssq += __shfl_down(ssq, off, 64);
  csum += __shfl_down(csum, 32, 64);
  __shared__ float scs[4 * 32];
  __shared__ float sss[4];
  int w = tid >> 6, lane = tid & 63;
  if (lane < 32) scs[w * 32 + lane] = csum;
  if (lane == 0) sss[w] = ssq;
  __syncthreads();
  if (tid < 32) atomicAdd(&stats[tid], scs[tid] + scs[32 + tid] + scs[64 + tid] + scs[96 + tid]);
  if (tid == 0) atomicAdd(&stats[32], sss[0] + sss[1] + sss[2] + sss[3]);
}
__global__ void pn_finalize(float* stats, float inv_n) {
  int f = threadIdx.x;
  float ssq = stats[32];
  float mu = (f < 32) ? stats[f] * inv_n : 0.f;
  float m2 = mu * mu;
#pragma unroll
  for (int off = 32; off >= 1; off >>= 1) m2 += __shfl_down(m2, off, 64);
  if (f < 32) stats[f] = mu;
  if (f == 0) stats[32] = rsqrtf(1e-5f + ssq * inv_n - m2);
}

// ---------------- small GEMM with fused pairnorm-apply + relu, bf16 out scaled by dinv ----------------
template <int FOUT>
__global__ void gemm_small_pn(const float* __restrict__ x, const float* __restrict__ W,
                              const float* __restrict__ stats, const float* __restrict__ dinv,
                              unsigned short* __restrict__ outb, int n) {
  __shared__ float Ws[32 * FOUT];
  __shared__ float mu[32];
  __shared__ float ssc[1];
  int t = threadIdx.x;
  for (int i = t; i < 32 * FOUT; i += blockDim.x) Ws[i] = W[i];
  if (t < 32) mu[t] = stats[t];
  if (t == 32) ssc[0] = stats[32];
  __syncthreads();
  float s = ssc[0];
  int idx = blockIdx.x * blockDim.x + t;
  int i = idx / FOUT, c = idx - i * FOUT;
  if (i >= n) return;
  const float* xr = x + (size_t)i * 32;
  float acc = 0.f;
#pragma unroll
  for (int k = 0; k < 32; ++k) {
    float v = (xr[k] - mu[k]) * s;
    v = v > 0.f ? v : 0.f;                  // relu
    acc += v * Ws[k * FOUT + c];
  }
  outb[(size_t)i * FOUT + c] = (unsigned short)f2bf(acc * dinv[i]);
}

// ---------------- launch ----------------
static inline int cdiv(long long a, long long b) { return (int)((a + b - 1) / b); }

extern "C" void kernel_launch(void* const* d_in, const int* in_sizes, int n_in,
                              void* d_out, int out_size, void* d_ws, size_t ws_size,
                              hipStream_t stream) {
  const float* x   = (const float*)d_in[0];
  const int*   ei  = (const int*)d_in[1];
  const float* W0  = (const float*)d_in[2];
  const float* b0  = (const float*)d_in[3];
  const float* W1  = (const float*)d_in[4];
  const float* b1  = (const float*)d_in[5];
  const float* Wf  = (const float*)d_in[6];
  const float* bfi = (const float*)d_in[7];
  float* out = (float*)d_out;

  int n = in_sizes[0] / 512;
  int e = in_sizes[1] / 2;
  const int* src = ei;
  const int* dst = ei + e;

  char* ws = (char*)d_ws;
  size_t o = 0;
  auto alloc = [&](size_t bytes) { char* p = ws + o; o = (o + bytes + 255) & ~(size_t)255; return p; };
  int*   cnt   = (int*)alloc((size_t)n * 4);
  float* dinv  = (float*)alloc((size_t)n * 4);
  float* stats = (float*)alloc(512);
  char*  hbuf  = alloc((size_t)n * 40 * 4);   // ebuf (e*4) / hb (n*32*2) / hb40 (n*40*2) time-share
  size_t fallback_need = o;
  int*   rowptr = (int*)alloc((size_t)(n + 1) * 4);
  int*   blksum = (int*)alloc(1024);
  int*   blkoff = (int*)alloc(1024);
  int*   bucket_cnt  = (int*)alloc(256 * 4);
  int*   bucket_base = (int*)alloc(257 * 4);
  int*   gcursor     = (int*)alloc(256 * 4);
  int*   ssrc   = (int*)alloc((size_t)e * 4);
  size_t csr_need = o;

  int* ebuf = (int*)hbuf;                       // dead before gemm0 writes hb
  unsigned short* hb   = (unsigned short*)hbuf; // n*32 bf16
  unsigned short* hb40 = (unsigned short*)hbuf; // n*40 bf16
  float* bufB = out;        // d_out doubles as fp32 ping-pong buffer (N*40 >= N*32)
  float* stats0 = stats;
  float* stats1 = stats + 64;

  int NBk = cdiv(n, NPB);       // dst buckets
  int nb2 = cdiv(n, 1024);      // scan1 blocks
  bool use_csr = (ws_size >= csr_need) && (n <= 131072) && (NBk <= 256) && (nb2 <= 256) &&
                 ((size_t)n * 40 * 4 >= (size_t)e * 4);

  if (use_csr) {
    zero_int<<<1, 256, 0, stream>>>(bucket_cnt, NBk);
    bucket_hist<<<cdiv(e, EPB), 256, 0, stream>>>(dst, bucket_cnt, e, NBk);
    bucket_scan<<<1, 256, 0, stream>>>(bucket_cnt, bucket_base, gcursor, NBk, e);
    bucket_partition<<<cdiv(e, EPB), 256, 0, stream>>>(src, dst, gcursor, ebuf, e, NBk);
    node_count<<<NBk, 256, 0, stream>>>(ebuf, bucket_base, cnt, dinv, n);
    scan1<<<nb2, 256, 0, stream>>>(cnt, rowptr, blksum, n);
    scan2<<<1, 256, 0, stream>>>(blksum, blkoff, nb2);
    scan3<<<cdiv(n, 256), 256, 0, stream>>>(rowptr, blkoff, n, e);
    bucket_scatter<<<NBk, 256, 0, stream>>>(ebuf, bucket_base, rowptr, ssrc, n);
  } else {
    zero_int<<<cdiv(n, 256), 256, 0, stream>>>(cnt, n);
    count_dst<<<cdiv(e, 256), 256, 0, stream>>>(dst, cnt, e);
    make_dinv2<<<cdiv(n, 256), 256, 0, stream>>>(cnt, dinv, n);
  }
  zero_stats<<<1, 128, 0, stream>>>(stats);

  // layer 0
  gemm0_mfma<<<cdiv(n, 64), 256, 0, stream>>>(x, W0, dinv, hb, n);
  if (use_csr) {
    agg_gather32<<<cdiv(n, 4), 256, 0, stream>>>(hb, dinv, b0, rowptr, ssrc, bufB, n);
  } else {
    agg_init<32><<<cdiv((long long)n * 32, 256), 256, 0, stream>>>(hb, dinv, b0, bufB, n);
    agg_edges<32><<<cdiv((long long)e * 32, 256), 256, 0, stream>>>(hb, dinv, src, dst, bufB, e);
  }
  pn_stats<<<400, 256, 0, stream>>>(bufB, stats0, n);
  pn_finalize<<<1, 64, 0, stream>>>(stats0, 1.0f / n);

  // layer 1 (pairnorm-apply fused into gemm prologue)
  gemm_small_pn<32><<<cdiv((long long)n * 32, 256), 256, 0, stream>>>(bufB, W1, stats0, dinv, hb, n);
  if (use_csr) {
    agg_gather32<<<cdiv(n, 4), 256, 0, stream>>>(hb, dinv, b1, rowptr, ssrc, bufB, n);
  } else {
    agg_init<32><<<cdiv((long long)n * 32, 256), 256, 0, stream>>>(hb, dinv, b1, bufB, n);
    agg_edges<32><<<cdiv((long long)e * 32, 256), 256, 0, stream>>>(hb, dinv, src, dst, bufB, e);
  }
  pn_stats<<<400, 256, 0, stream>>>(bufB, stats1, n);
  pn_finalize<<<1, 64, 0, stream>>>(stats1, 1.0f / n);

  // final layer (gemm consumes bufB=d_out before agg rewrites d_out)
  gemm_small_pn<40><<<cdiv((long long)n * 40, 320), 320, 0, stream>>>(bufB, Wf, stats1, dinv, hb40, n);
  if (use_csr) {
    agg_gather40<<<cdiv(n, 4), 256, 0, stream>>>(hb40, dinv, bfi, rowptr, ssrc, out, n);
  } else {
    agg_init<40><<<cdiv((long long)n * 40, 256), 256, 0, stream>>>(hb40, dinv, bfi, out, n);
    agg_edges<40><<<cdiv((long long)e * 40, 256), 256, 0, stream>>>(hb40, dinv, src, dst, out, e);
  }
}

// Round 8
// 669.808 us; speedup vs baseline: 1.2178x; 1.2178x over previous
//
#include <hip/hip_runtime.h>
#include <hip/hip_bf16.h>

typedef __attribute__((ext_vector_type(8))) short bf16x8;
typedef __attribute__((ext_vector_type(4))) float f32x4;

#define NPB 512      // nodes per dst-bucket (9 bits)
#define EPB 8192     // edges per partition/hist block

static __device__ __forceinline__ short f2bf(float v) {
  __hip_bfloat16 b = __float2bfloat16(v);   // RNE
  return __builtin_bit_cast(short, b);
}
static __device__ __forceinline__ float bf2f(unsigned short u) {
  union { unsigned u; float f; } c; c.u = (unsigned)u << 16; return c.f;
}

// ---------------- generic ----------------
__global__ void zero_int(int* p, int n) {
  int i = blockIdx.x * blockDim.x + threadIdx.x;
  if (i < n) p[i] = 0;
}
__global__ void make_dinv2(const int* __restrict__ cnt, float* __restrict__ dinv, int n) {
  int i = blockIdx.x * blockDim.x + threadIdx.x;
  if (i < n) dinv[i] = rsqrtf(1.0f + (float)cnt[i]);   // +1 self loop
}

// ---------------- bucketed CSR build ----------------
__global__ __launch_bounds__(256) void bucket_hist(const int* __restrict__ dst,
                                                   int* __restrict__ bucket_cnt, int e, int nb) {
  __shared__ int lh[256];
  int t = threadIdx.x;
  lh[t] = 0;
  __syncthreads();
  int c0 = blockIdx.x * EPB, c1 = min(c0 + EPB, e);
  for (int i = c0 + t; i < c1; i += 256) atomicAdd(&lh[dst[i] >> 9], 1);
  __syncthreads();
  if (t < nb && lh[t] > 0) atomicAdd(&bucket_cnt[t], lh[t]);
}
__global__ void bucket_scan(const int* __restrict__ bucket_cnt, int* __restrict__ base,
                            int* __restrict__ gcursor, int nb, int e) {
  __shared__ int s[256];
  int t = threadIdx.x;
  int v = (t < nb) ? bucket_cnt[t] : 0;
  s[t] = v;
  __syncthreads();
  for (int off = 1; off < 256; off <<= 1) {
    int val = (t >= off) ? s[t - off] : 0;
    __syncthreads();
    s[t] += val;
    __syncthreads();
  }
  if (t < nb) { int b = s[t] - v; base[t] = b; gcursor[t] = b; }
  if (t == 0) base[nb] = e;
}
// packed entry: (local_dst[9b] << 17) | src[17b]   (requires n <= 131072)
__global__ __launch_bounds__(256) void bucket_partition(const int* __restrict__ src,
    const int* __restrict__ dst, int* __restrict__ gcursor, int* __restrict__ ebuf,
    int e, int nb) {
  __shared__ int lh[256];
  __shared__ int lbase[256];
  int t = threadIdx.x;
  lh[t] = 0;
  __syncthreads();
  int c0 = blockIdx.x * EPB, c1 = min(c0 + EPB, e);
  for (int i = c0 + t; i < c1; i += 256) atomicAdd(&lh[dst[i] >> 9], 1);
  __syncthreads();
  if (t < nb && lh[t] > 0) lbase[t] = atomicAdd(&gcursor[t], lh[t]);
  lh[t] = 0;           // becomes per-bucket rank cursor
  __syncthreads();
  for (int i = c0 + t; i < c1; i += 256) {
    int d = dst[i], b = d >> 9;
    int r = atomicAdd(&lh[b], 1);
    ebuf[lbase[b] + r] = ((d & (NPB - 1)) << 17) | src[i];
  }
}
__global__ __launch_bounds__(256) void node_count(const int* __restrict__ ebuf,
    const int* __restrict__ base, int* __restrict__ cnt, float* __restrict__ dinv, int n) {
  __shared__ int lc[NPB];
  int b = blockIdx.x;
  for (int i = threadIdx.x; i < NPB; i += 256) lc[i] = 0;
  __syncthreads();
  int b0 = base[b], b1 = base[b + 1];
  for (int i = b0 + threadIdx.x; i < b1; i += 256) atomicAdd(&lc[ebuf[i] >> 17], 1);
  __syncthreads();
  int g0 = b * NPB;
  for (int i = threadIdx.x; i < NPB; i += 256)
    if (g0 + i < n) {
      int c = lc[i];
      cnt[g0 + i] = c;
      dinv[g0 + i] = rsqrtf(1.0f + (float)c);
    }
}
// exclusive scan over n node counts -> rowptr[n+1]
__global__ __launch_bounds__(256) void scan1(const int* __restrict__ cnt, int* __restrict__ excl,
                                             int* __restrict__ blksum, int n) {
  __shared__ int tsum[256];
  int t = threadIdx.x;
  int idx = blockIdx.x * 1024 + t * 4;
  int4 v = {0, 0, 0, 0};
  if (idx + 3 < n) v = *(const int4*)(cnt + idx);
  else {
    if (idx < n) v.x = cnt[idx];
    if (idx + 1 < n) v.y = cnt[idx + 1];
    if (idx + 2 < n) v.z = cnt[idx + 2];
    if (idx + 3 < n) v.w = cnt[idx + 3];
  }
  int s = v.x + v.y + v.z + v.w;
  tsum[t] = s;
  __syncthreads();
  for (int off = 1; off < 256; off <<= 1) {
    int val = (t >= off) ? tsum[t - off] : 0;
    __syncthreads();
    tsum[t] += val;
    __syncthreads();
  }
  int e0 = tsum[t] - s;
  if (idx < n) excl[idx] = e0;
  if (idx + 1 < n) excl[idx + 1] = e0 + v.x;
  if (idx + 2 < n) excl[idx + 2] = e0 + v.x + v.y;
  if (idx + 3 < n) excl[idx + 3] = e0 + v.x + v.y + v.z;
  if (t == 255) blksum[blockIdx.x] = tsum[255];
}
__global__ void scan2(const int* __restrict__ blksum, int* __restrict__ blkoff, int nb) {
  __shared__ int s[256];
  int t = threadIdx.x;
  int v0 = (t < nb) ? blksum[t] : 0;
  s[t] = v0;
  __syncthreads();
  for (int off = 1; off < 256; off <<= 1) {
    int val = (t >= off) ? s[t - off] : 0;
    __syncthreads();
    s[t] += val;
    __syncthreads();
  }
  if (t < nb) blkoff[t] = s[t] - v0;
}
__global__ void scan3(int* __restrict__ rowptr, const int* __restrict__ blkoff, int n, int e) {
  int i = blockIdx.x * blockDim.x + threadIdx.x;
  if (i < n) rowptr[i] += blkoff[i >> 10];
  if (i == 0) rowptr[n] = e;
}
__global__ __launch_bounds__(256) void bucket_scatter(const int* __restrict__ ebuf,
    const int* __restrict__ base, const int* __restrict__ rowptr,
    int* __restrict__ ssrc, int n) {
  __shared__ int lcur[NPB];
  int b = blockIdx.x;
  int g0 = b * NPB;
  for (int i = threadIdx.x; i < NPB; i += 256)
    lcur[i] = (g0 + i < n) ? rowptr[g0 + i] : 0;
  __syncthreads();
  int b0 = base[b], b1 = base[b + 1];
  for (int i = b0 + threadIdx.x; i < b1; i += 256) {
    int p = ebuf[i];
    int pos = atomicAdd(&lcur[p >> 17], 1);
    ssrc[pos] = p & 0x1FFFF;
  }
}

// ---------------- GEMM0: [n,512] x [512,32], bf16 MFMA, bf16 out scaled by dinv ----------------
__global__ __launch_bounds__(256) void gemm0_mfma(
    const float* __restrict__ x, const float* __restrict__ W,
    const float* __restrict__ dinv, unsigned short* __restrict__ hb, int n) {
  __shared__ bf16x8 wp[2048];               // [ct(2)][ks(16)][lane(64)], 32KB
  int tid = threadIdx.x;
  for (int s = tid; s < 2048; s += 256) {
    int ct = s >> 10, rem = s & 1023, ks = rem >> 6, lane = rem & 63;
    int r = lane & 15, half = lane >> 4;
    int k0 = ks * 32 + half * 8;
    bf16x8 tmp;
#pragma unroll
    for (int j = 0; j < 8; ++j)
      tmp[j] = f2bf(W[(k0 + j) * 32 + ct * 16 + r]);
    wp[s] = tmp;
  }
  __syncthreads();
  int wave = tid >> 6, lane = tid & 63;
  int rowbase = blockIdx.x * 64 + wave * 16;
  int r = lane & 15, half = lane >> 4;
  int arow = rowbase + r; if (arow > n - 1) arow = n - 1;
  const float* xr = x + (size_t)arow * 512 + half * 8;
  f32x4 acc0 = {0.f, 0.f, 0.f, 0.f}, acc1 = {0.f, 0.f, 0.f, 0.f};
#pragma unroll
  for (int ks = 0; ks < 16; ++ks) {
    f32x4 a0 = *(const f32x4*)(xr + ks * 32);
    f32x4 a1 = *(const f32x4*)(xr + ks * 32 + 4);
    bf16x8 af;
    af[0] = f2bf(a0[0]); af[1] = f2bf(a0[1]); af[2] = f2bf(a0[2]); af[3] = f2bf(a0[3]);
    af[4] = f2bf(a1[0]); af[5] = f2bf(a1[1]); af[6] = f2bf(a1[2]); af[7] = f2bf(a1[3]);
    acc0 = __builtin_amdgcn_mfma_f32_16x16x32_bf16(af, wp[ks * 64 + lane], acc0, 0, 0, 0);
    acc1 = __builtin_amdgcn_mfma_f32_16x16x32_bf16(af, wp[1024 + ks * 64 + lane], acc1, 0, 0, 0);
  }
#pragma unroll
  for (int rg = 0; rg < 4; ++rg) {
    int row = rowbase + half * 4 + rg;      // C/D: col=lane&15, row=(lane>>4)*4+reg
    if (row < n) {
      float dv = dinv[row];
      hb[(size_t)row * 32 + r]      = (unsigned short)f2bf(acc0[rg] * dv);
      hb[(size_t)row * 32 + 16 + r] = (unsigned short)f2bf(acc1[rg] * dv);
    }
  }
}

// ---------------- vectorized gather aggregation ----------------
// lane = 8q+p: lane loads uint2 (4 bf16 feats) of row s_q; 8 rows per load-inst.
// out[d] = bias + dinv[d] * ( hb[d] + sum_{s in row d} hb[s] );  hb pre-scaled by dinv[src]
__global__ __launch_bounds__(256) void agg_gather32v(
    const unsigned short* __restrict__ hb, const float* __restrict__ dinv,
    const float* __restrict__ bias, const int* __restrict__ rowptr,
    const int* __restrict__ ssrc, float* __restrict__ out, int n) {
  const uint2* hbu2 = (const uint2*)hb;     // 8 uint2 per 32-feat row
  int wid = (int)((blockIdx.x * 256u + threadIdx.x) >> 6);
  int lane = threadIdx.x & 63;
  if (wid >= n) return;
  int p = lane & 7, q = lane >> 3;
  int r0 = rowptr[wid], r1 = rowptr[wid + 1];
  f32x4 acc = {0.f, 0.f, 0.f, 0.f};
  for (int base = r0; base < r1; base += 64) {
    int cnt = min(64, r1 - base);
    int idx = ssrc[base + min(lane, cnt - 1)];   // coalesced preload
#pragma unroll 1
    for (int g = 0; g < cnt; g += 16) {
#pragma unroll
      for (int u = 0; u < 2; ++u) {
        int k = g + q + 8 * u;
        int s = __shfl(idx, min(k, cnt - 1), 64);
        uint2 v = hbu2[(size_t)s * 8 + p];
        float w = (k < cnt) ? 1.f : 0.f;
        acc[0] += w * bf2f((unsigned short)(v.x & 0xffff));
        acc[1] += w * bf2f((unsigned short)(v.x >> 16));
        acc[2] += w * bf2f((unsigned short)(v.y & 0xffff));
        acc[3] += w * bf2f((unsigned short)(v.y >> 16));
      }
    }
  }
#pragma unroll
  for (int off = 8; off <= 32; off <<= 1) {
    acc[0] += __shfl_down(acc[0], off, 64);
    acc[1] += __shfl_down(acc[1], off, 64);
    acc[2] += __shfl_down(acc[2], off, 64);
    acc[3] += __shfl_down(acc[3], off, 64);
  }
  if (lane < 8) {
    uint2 sv = hbu2[(size_t)wid * 8 + p];
    f32x4 b4 = *(const f32x4*)(bias + 4 * p);
    float di = dinv[wid];
    f32x4 res;
    res[0] = b4[0] + di * (bf2f((unsigned short)(sv.x & 0xffff)) + acc[0]);
    res[1] = b4[1] + di * (bf2f((unsigned short)(sv.x >> 16))    + acc[1]);
    res[2] = b4[2] + di * (bf2f((unsigned short)(sv.y & 0xffff)) + acc[2]);
    res[3] = b4[3] + di * (bf2f((unsigned short)(sv.y >> 16))    + acc[3]);
    *(f32x4*)(out + (size_t)wid * 32 + 4 * p) = res;
  }
}

// ---------------- fallback atomic path (bf16 hb, 32-wide only) ----------------
__global__ void count_dst(const int* __restrict__ dst, int* __restrict__ cnt, int e) {
  int i = blockIdx.x * blockDim.x + threadIdx.x;
  if (i < e) atomicAdd(&cnt[dst[i]], 1);
}
__global__ void agg_init32(const unsigned short* __restrict__ hb, const float* __restrict__ dinv,
                           const float* __restrict__ bias, float* __restrict__ out, int n) {
  int idx = blockIdx.x * blockDim.x + threadIdx.x;
  if (idx >= n * 32) return;
  int i = idx >> 5, f = idx & 31;
  out[idx] = bias[f] + bf2f(hb[idx]) * dinv[i];
}
__global__ void agg_edges32(const unsigned short* __restrict__ hb, const float* __restrict__ dinv,
                            const int* __restrict__ src, const int* __restrict__ dst,
                            float* __restrict__ out, int e) {
  int t = blockIdx.x * blockDim.x + threadIdx.x;
  int edge = t >> 5, f = t & 31;
  if (edge >= e) return;
  int s = src[edge], d = dst[edge];
  atomicAdd(&out[d * 32 + f], bf2f(hb[s * 32 + f]) * dinv[d]);
}

// ---------------- pairnorm stats ----------------
__global__ void zero_stats(float* stats) {
  if (threadIdx.x < 192) stats[threadIdx.x] = 0.f;   // stats0, stats1, zbias
}
__global__ void pn_stats(const float* __restrict__ x, float* __restrict__ stats, int n) {
  int tid = threadIdx.x;
  int gsize = gridDim.x * blockDim.x;
  float csum = 0.f, ssq = 0.f;
  for (int idx = blockIdx.x * blockDim.x + tid; idx < n * 32; idx += gsize) {
    float v = x[idx];
    csum += v; ssq += v * v;
  }
#pragma unroll
  for (int off = 32; off >= 1; off >>= 1) ssq += __shfl_down(ssq, off, 64);
  csum += __shfl_down(csum, 32, 64);
  __shared__ float scs[4 * 32];
  __shared__ float sss[4];
  int w = tid >> 6, lane = tid & 63;
  if (lane < 32) scs[w * 32 + lane] = csum;
  if (lane == 0) sss[w] = ssq;
  __syncthreads();
  if (tid < 32) atomicAdd(&stats[tid], scs[tid] + scs[32 + tid] + scs[64 + tid] + scs[96 + tid]);
  if (tid == 0) atomicAdd(&stats[32], sss[0] + sss[1] + sss[2] + sss[3]);
}
__global__ void pn_finalize(float* stats, float inv_n) {
  int f = threadIdx.x;
  float ssq = stats[32];
  float mu = (f < 32) ? stats[f] * inv_n : 0.f;
  float m2 = mu * mu;
#pragma unroll
  for (int off = 32; off >= 1; off >>= 1) m2 += __shfl_down(m2, off, 64);
  if (f < 32) stats[f] = mu;
  if (f == 0) stats[32] = rsqrtf(1e-5f + ssq * inv_n - m2);
}

// ---------------- small GEMM with fused pairnorm-apply + relu, bf16 out scaled by dinv ----------------
__global__ void gemm_small_pn32(const float* __restrict__ x, const float* __restrict__ W,
                                const float* __restrict__ stats, const float* __restrict__ dinv,
                                unsigned short* __restrict__ outb, int n) {
  __shared__ float Ws[32 * 32];
  __shared__ float mu[32];
  __shared__ float ssc[1];
  int t = threadIdx.x;
  for (int i = t; i < 32 * 32; i += blockDim.x) Ws[i] = W[i];
  if (t < 32) mu[t] = stats[t];
  if (t == 32) ssc[0] = stats[32];
  __syncthreads();
  float s = ssc[0];
  int idx = blockIdx.x * blockDim.x + t;
  int i = idx >> 5, c = idx & 31;
  if (i >= n) return;
  const float* xr = x + (size_t)i * 32;
  float acc = 0.f;
#pragma unroll
  for (int k = 0; k < 32; ++k) {
    float v = (xr[k] - mu[k]) * s;
    v = v > 0.f ? v : 0.f;                  // relu
    acc += v * Ws[k * 32 + c];
  }
  outb[(size_t)i * 32 + c] = (unsigned short)f2bf(acc * dinv[i]);
}

// ---------------- pn-apply + relu + dinv-scale -> bf16 (for commuted final layer) ----------------
__global__ void pn_relu_bf16(const float* __restrict__ x, const float* __restrict__ stats,
                             const float* __restrict__ dinv, unsigned short* __restrict__ outb, int n) {
  __shared__ float mu[32];
  __shared__ float ssc[1];
  int t = threadIdx.x;
  if (t < 32) mu[t] = stats[t];
  if (t == 32) ssc[0] = stats[32];
  __syncthreads();
  float s = ssc[0];
  int idx = blockIdx.x * blockDim.x + t;
  if (idx >= n * 32) return;
  int i = idx >> 5, f = idx & 31;
  float v = (x[idx] - mu[f]) * s;
  v = v > 0.f ? v : 0.f;
  outb[idx] = (unsigned short)f2bf(v * dinv[i]);
}

// ---------------- plain small GEMM [n,32]x[32,40] + bias, fp32 out ----------------
__global__ void gemm_small40(const float* __restrict__ x, const float* __restrict__ W,
                             const float* __restrict__ bias, float* __restrict__ out, int n) {
  __shared__ float Ws[32 * 40];
  int t = threadIdx.x;
  for (int i = t; i < 32 * 40; i += blockDim.x) Ws[i] = W[i];
  __syncthreads();
  int idx = blockIdx.x * blockDim.x + t;
  int i = idx / 40, c = idx - i * 40;
  if (i >= n) return;
  const float* xr = x + (size_t)i * 32;
  float acc = 0.f;
#pragma unroll
  for (int k = 0; k < 32; ++k) acc += xr[k] * Ws[k * 40 + c];
  out[(size_t)i * 40 + c] = acc + bias[c];
}

// ---------------- launch ----------------
static inline int cdiv(long long a, long long b) { return (int)((a + b - 1) / b); }

extern "C" void kernel_launch(void* const* d_in, const int* in_sizes, int n_in,
                              void* d_out, int out_size, void* d_ws, size_t ws_size,
                              hipStream_t stream) {
  const float* x   = (const float*)d_in[0];
  const int*   ei  = (const int*)d_in[1];
  const float* W0  = (const float*)d_in[2];
  const float* b0  = (const float*)d_in[3];
  const float* W1  = (const float*)d_in[4];
  const float* b1  = (const float*)d_in[5];
  const float* Wf  = (const float*)d_in[6];
  const float* bfi = (const float*)d_in[7];
  float* out = (float*)d_out;

  int n = in_sizes[0] / 512;
  int e = in_sizes[1] / 2;
  const int* src = ei;
  const int* dst = ei + e;

  char* ws = (char*)d_ws;
  size_t o = 0;
  auto alloc = [&](size_t bytes) { char* p = ws + o; o = (o + bytes + 255) & ~(size_t)255; return p; };
  int*   cnt   = (int*)alloc((size_t)n * 4);
  float* dinv  = (float*)alloc((size_t)n * 4);
  float* stats = (float*)alloc(1024);
  char*  hbuf  = alloc((size_t)n * 40 * 4);   // ebuf (e*4) / hb (n*32*2) time-share
  float* bufC  = (float*)alloc((size_t)n * 32 * 4);   // aggregated pre-final fp32
  size_t fallback_need = o;
  int*   rowptr = (int*)alloc((size_t)(n + 1) * 4);
  int*   blksum = (int*)alloc(1024);
  int*   blkoff = (int*)alloc(1024);
  int*   bucket_cnt  = (int*)alloc(256 * 4);
  int*   bucket_base = (int*)alloc(257 * 4);
  int*   gcursor     = (int*)alloc(256 * 4);
  int*   ssrc   = (int*)alloc((size_t)e * 4);
  size_t csr_need = o;

  int* ebuf = (int*)hbuf;                       // dead before gemm0 writes hb
  unsigned short* hb = (unsigned short*)hbuf;   // n*32 bf16
  float* bufB = out;        // d_out doubles as fp32 ping-pong buffer (N*40 >= N*32)
  float* stats0 = stats;
  float* stats1 = stats + 64;
  float* zbias  = stats + 128;   // 32 zeros (zeroed by zero_stats)

  int NBk = cdiv(n, NPB);       // dst buckets
  int nb2 = cdiv(n, 1024);      // scan1 blocks
  bool use_csr = (ws_size >= csr_need) && (n <= 131072) && (NBk <= 256) && (nb2 <= 256) &&
                 ((size_t)n * 40 * 4 >= (size_t)e * 4);

  if (use_csr) {
    zero_int<<<1, 256, 0, stream>>>(bucket_cnt, NBk);
    bucket_hist<<<cdiv(e, EPB), 256, 0, stream>>>(dst, bucket_cnt, e, NBk);
    bucket_scan<<<1, 256, 0, stream>>>(bucket_cnt, bucket_base, gcursor, NBk, e);
    bucket_partition<<<cdiv(e, EPB), 256, 0, stream>>>(src, dst, gcursor, ebuf, e, NBk);
    node_count<<<NBk, 256, 0, stream>>>(ebuf, bucket_base, cnt, dinv, n);
    scan1<<<nb2, 256, 0, stream>>>(cnt, rowptr, blksum, n);
    scan2<<<1, 256, 0, stream>>>(blksum, blkoff, nb2);
    scan3<<<cdiv(n, 256), 256, 0, stream>>>(rowptr, blkoff, n, e);
    bucket_scatter<<<NBk, 256, 0, stream>>>(ebuf, bucket_base, rowptr, ssrc, n);
  } else {
    zero_int<<<cdiv(n, 256), 256, 0, stream>>>(cnt, n);
    count_dst<<<cdiv(e, 256), 256, 0, stream>>>(dst, cnt, e);
    make_dinv2<<<cdiv(n, 256), 256, 0, stream>>>(cnt, dinv, n);
  }
  zero_stats<<<1, 256, 0, stream>>>(stats);

  // layer 0
  gemm0_mfma<<<cdiv(n, 64), 256, 0, stream>>>(x, W0, dinv, hb, n);
  if (use_csr) {
    agg_gather32v<<<cdiv(n, 4), 256, 0, stream>>>(hb, dinv, b0, rowptr, ssrc, bufB, n);
  } else {
    agg_init32<<<cdiv((long long)n * 32, 256), 256, 0, stream>>>(hb, dinv, b0, bufB, n);
    agg_edges32<<<cdiv((long long)e * 32, 256), 256, 0, stream>>>(hb, dinv, src, dst, bufB, e);
  }
  pn_stats<<<400, 256, 0, stream>>>(bufB, stats0, n);
  pn_finalize<<<1, 64, 0, stream>>>(stats0, 1.0f / n);

  // layer 1 (pairnorm-apply fused into gemm prologue)
  gemm_small_pn32<<<cdiv((long long)n * 32, 256), 256, 0, stream>>>(bufB, W1, stats0, dinv, hb, n);
  if (use_csr) {
    agg_gather32v<<<cdiv(n, 4), 256, 0, stream>>>(hb, dinv, b1, rowptr, ssrc, bufB, n);
  } else {
    agg_init32<<<cdiv((long long)n * 32, 256), 256, 0, stream>>>(hb, dinv, b1, bufB, n);
    agg_edges32<<<cdiv((long long)e * 32, 256), 256, 0, stream>>>(hb, dinv, src, dst, bufB, e);
  }
  pn_stats<<<400, 256, 0, stream>>>(bufB, stats1, n);
  pn_finalize<<<1, 64, 0, stream>>>(stats1, 1.0f / n);

  // final layer, COMMUTED: out = (Â pn_relu(h2)) Wf + bf
  pn_relu_bf16<<<cdiv((long long)n * 32, 256), 256, 0, stream>>>(bufB, stats1, dinv, hb, n);
  if (use_csr) {
    agg_gather32v<<<cdiv(n, 4), 256, 0, stream>>>(hb, dinv, zbias, rowptr, ssrc, bufC, n);
  } else {
    agg_init32<<<cdiv((long long)n * 32, 256), 256, 0, stream>>>(hb, dinv, zbias, bufC, n);
    agg_edges32<<<cdiv((long long)e * 32, 256), 256, 0, stream>>>(hb, dinv, src, dst, bufC, e);
  }
  gemm_small40<<<cdiv((long long)n * 40, 320), 320, 0, stream>>>(bufC, Wf, bfi, out, n);
}